// Round 8
// baseline (305.804 us; speedup 1.0000x reference)
//
#include <hip/hip_runtime.h>

#define ENC 50
#define NT 20
#define TEMPC 5.0f
#define HSTRIDE 72   // bf16 slots per batch row in LDS h-tile (64 used + pad)
#define L2E 1.4426950408889634f
#define NTILE 13
#define NREG 4       // A tiles 0..3 in registers
#define NLDS 9       // A tiles 4..12 in LDS

typedef __attribute__((ext_vector_type(8))) short bf16x8;
typedef __attribute__((ext_vector_type(4))) float f32x4;

__device__ __forceinline__ unsigned short f2bf(float x) {
  union { float f; unsigned u; } cv; cv.f = x;
  unsigned u = cv.u;
  u += 0x7FFFu + ((u >> 16) & 1u);   // RNE
  return (unsigned short)(u >> 16);
}

// k-slot layout of h~ row (64 slots): slot 14q+j (q=0..3, j=0..12) = feature 13q+j
// (features >=50 are zero-pads); j=13 pad; slot 56=z0, 57=z1, 58=const1, 59..63 pad.
// A perm: fragment m, subrow 4*pa+r -> feature 13*pa+m, gate r (i,f,g,o).
// exp2-domain prefold: gates i/f/o scaled -log2e, gate g +2*log2e.
__device__ __forceinline__ float a_elem(int m, int lane, int kt, int e,
                                        const float* U, const float* Wl,
                                        const float* bl) {
  int sub = lane & 15;
  int pa = sub >> 2, r = sub & 3;
  int feat = 13 * pa + m;
  int k = 32 * kt + 8 * (lane >> 4) + e;
  float val = 0.f;
  if (feat < ENC) {
    int col = r * ENC + feat;
    if (k < 56) {
      int pk = k / 14, j = k - 14 * pk;
      int fin = 13 * pk + j;
      if (j < 13 && fin < ENC) val = U[fin * 4 * ENC + col];
    } else if (k == 56) val = Wl[col];
    else if (k == 57)   val = Wl[4 * ENC + col];
    else if (k == 58)   val = bl[col];
  }
  return val * ((r == 2) ? (2.0f * L2E) : (-L2E));
}

__global__ void idm_prep(const float* __restrict__ U, const float* __restrict__ Wl,
                         const float* __restrict__ bl, const float* __restrict__ Wa,
                         const float* __restrict__ ba, const float* __restrict__ Wn,
                         const float* __restrict__ bn,
                         unsigned short* __restrict__ Afrag, float* __restrict__ wcomb) {
  int tid = blockIdx.x * blockDim.x + threadIdx.x;
  for (int idx = tid; idx < 2 * NTILE * 64; idx += blockDim.x * gridDim.x) {
    int frag = idx >> 6, lane = idx & 63;
    int m = frag >> 1, kt = frag & 1;
    unsigned short o[8];
#pragma unroll
    for (int e = 0; e < 8; ++e) o[e] = f2bf(a_elem(m, lane, kt, e, U, Wl, bl));
#pragma unroll
    for (int e = 0; e < 8; ++e) Afrag[idx * 8 + e] = o[e];
  }
  if (tid < 52) {
    float s = 0.f;
    if (tid < ENC) { for (int j = 0; j < ENC; ++j) s += Wa[tid * ENC + j] * Wn[j]; }
    wcomb[tid] = s * (-TEMPC * L2E);
  }
  if (tid == 52) {
    float s = bn[0];
    for (int j = 0; j < ENC; ++j) s += ba[j] * Wn[j];
    wcomb[52] = s * (-TEMPC * L2E);
  }
}

template <int PRE>
__global__ __launch_bounds__(256, 3) void idm_main(
    const float* __restrict__ s_in, const float* __restrict__ zin,
    const float* __restrict__ dvp, const float* __restrict__ tgp,
    const float* __restrict__ jxp, const float* __restrict__ map,
    const float* __restrict__ mip, const float* __restrict__ h0,
    const float* __restrict__ c0,
    const unsigned short* __restrict__ Afrag, const float* __restrict__ wcomb,
    const float* __restrict__ U, const float* __restrict__ Wl, const float* __restrict__ bl,
    const float* __restrict__ Wa, const float* __restrict__ ba,
    const float* __restrict__ Wn, const float* __restrict__ bn,
    float* __restrict__ out_act, float* __restrict__ out_att, int Btot) {
  __shared__ __align__(16) unsigned short AldT[NLDS * 2 * 64 * 8];
  __shared__ __align__(16) unsigned short hlds[4 * 16 * HSTRIDE];
  __shared__ float wcl[64];
  const int tid = threadIdx.x;
  const int wid = tid >> 6, lane = tid & 63;
  const int v = lane & 15, p = lane >> 4;
  int b = blockIdx.x * 64 + wid * 16 + v;
  if (b >= Btot) b = Btot - 1;   // benign duplicate work

  bf16x8 Ar[NREG][2];
  float wc[NTILE], bcomb;
  if (PRE) {
#pragma unroll
    for (int m = 0; m < NREG; ++m) {
      Ar[m][0] = ((const bf16x8*)Afrag)[(2 * m) * 64 + lane];
      Ar[m][1] = ((const bf16x8*)Afrag)[(2 * m + 1) * 64 + lane];
    }
    {
      f32x4* dst = (f32x4*)AldT;
      const f32x4* src = (const f32x4*)Afrag + NREG * 2 * 64;
      for (int i = tid; i < NLDS * 2 * 64; i += 256) dst[i] = src[i];
    }
#pragma unroll
    for (int m = 0; m < NTILE; ++m) wc[m] = wcomb[13 * p + m];
    bcomb = wcomb[52];
  } else {
    if (tid < 53) {
      float s;
      if (tid < ENC) {
        s = 0.f;
        for (int j = 0; j < ENC; ++j) s += Wa[tid * ENC + j] * Wn[j];
      } else if (tid < 52) {
        s = 0.f;
      } else {
        s = bn[0];
        for (int j = 0; j < ENC; ++j) s += ba[j] * Wn[j];
      }
      wcl[tid] = s * (-TEMPC * L2E);
    } else if (tid < 64) {
      wcl[tid] = 0.f;
    }
#pragma unroll
    for (int m = 0; m < NREG; ++m) {
#pragma unroll
      for (int kt = 0; kt < 2; ++kt) {
        bf16x8 a;
#pragma unroll
        for (int e = 0; e < 8; ++e) a[e] = (short)f2bf(a_elem(m, lane, kt, e, U, Wl, bl));
        Ar[m][kt] = a;
      }
    }
    for (int q = wid; q < NLDS * 2; q += 4) {   // waves split the LDS tiles
      int m = NREG + (q >> 1), kt = q & 1;
      unsigned short o[8];
#pragma unroll
      for (int e = 0; e < 8; ++e) o[e] = f2bf(a_elem(m, lane, kt, e, U, Wl, bl));
      bf16x8 a;
#pragma unroll
      for (int e = 0; e < 8; ++e) a[e] = (short)o[e];
      ((bf16x8*)AldT)[q * 64 + lane] = a;
    }
    __syncthreads();
#pragma unroll
    for (int m = 0; m < NTILE; ++m) wc[m] = wcl[13 * p + m];
    bcomb = wcl[52];
  }
  __syncthreads();   // A-LDS staged (and wcl in non-PRE)

  // per-row params (cached)
  const float amax = map[b], amin = mip[b];
  const float tgap = tgp[b], jamx = jxp[b];
  const float inv_dv = __builtin_amdgcn_rcpf(dvp[b]);
  const float inv2s = 0.5f * __builtin_amdgcn_rsqf(amax * amin);

  // c state: feature 13p+m of batch b
  float c[NTILE];
#pragma unroll
  for (int m = 0; m < NTILE; ++m) {
    int f = 13 * p + m;
    c[m] = (f < ENC) ? c0[(size_t)b * ENC + f] : 0.f;
  }

  // init h~ LDS region for this wave
  unsigned short* hl = &hlds[wid * 16 * HSTRIDE];
  for (int i = lane; i < 16 * HSTRIDE / 2; i += 64) ((unsigned*)hl)[i] = 0u;
#pragma unroll
  for (int m = 0; m < NTILE; ++m) {
    int f = 13 * p + m;
    float h00 = (f < ENC) ? h0[(size_t)b * ENC + f] : 0.f;
    hl[v * HSTRIDE + 14 * p + m] = f2bf(h00);
  }
  if (p == 0) {
    hl[v * HSTRIDE + 56] = f2bf(zin[(size_t)b * 2 + 0]);
    hl[v * HSTRIDE + 57] = f2bf(zin[(size_t)b * 2 + 1]);
    hl[v * HSTRIDE + 58] = (unsigned short)0x3F80; // bf16(1.0)
  }

  const float* srow = s_in + (size_t)b * (NT * 7);
  const size_t ob = (size_t)b * NT;
  const bf16x8* hv = (const bf16x8*)hl;
  const int sel = 3 * (p & 1);   // p even: leader; p odd: merger
  unsigned* hlw = (unsigned*)hl;
  const int wbase = v * 36 + 7 * p;        // dword index of this lane's h slots
  unsigned aoff = 0;                       // opaque: defeats LICM of A-LDS reads

#pragma unroll 1
  for (int t = 0; t < NT; ++t) {
    asm volatile("" : "+v"(aoff));
    const bf16x8* ATv = (const bf16x8*)AldT + aoff;
    // B-fragments: slots [8p,8p+8) and [32+8p, 32+8p+8) of row v
    bf16x8 B0 = hv[v * 9 + p];
    bf16x8 B1 = hv[v * 9 + 4 + p];
    f32x4 accbuf[2];
    {
      f32x4 z4 = {0.f, 0.f, 0.f, 0.f};
      f32x4 t0 = __builtin_amdgcn_mfma_f32_16x16x32_bf16(Ar[0][0], B0, z4, 0, 0, 0);
      accbuf[0] = __builtin_amdgcn_mfma_f32_16x16x32_bf16(Ar[0][1], B1, t0, 0, 0, 0);
    }
    float att_dot = 0.f;
    float hprev = 0.f;
#pragma unroll
    for (int m = 0; m < NTILE; ++m) {
      // seal each iteration: block cross-iteration hoisting of ds_reads
      __builtin_amdgcn_sched_barrier(0);
      bf16x8 x0, x1;
      if (m < NTILE - 1) {   // fetch next tile's fragments early
        if (m + 1 < NREG) {
          x0 = Ar[m + 1][0]; x1 = Ar[m + 1][1];
        } else {
          int q = (m + 1 - NREG) * 2;
          x0 = ATv[q * 64 + lane];
          x1 = ATv[(q + 1) * 64 + lane];
        }
      }
      f32x4 acc = accbuf[m & 1];
      // lane-local LSTM cell in exp2 domain: acc = {-i*L2E, -f*L2E, 2g*L2E, -o*L2E}
      float a  = __builtin_amdgcn_exp2f(acc[0]);   // e^{-i}
      float bb = __builtin_amdgcn_exp2f(acc[1]);   // e^{-f}
      float G  = __builtin_amdgcn_exp2f(acc[2]);   // e^{2g}
      float d  = __builtin_amdgcn_exp2f(acc[3]);   // e^{-o}
      float R = 1.f + a, P = 1.f + bb, Q = G + 1.f;
      float QR = Q * R;
      float num = fmaf(G - 1.f, P, c[m] * QR);
      float cn = num * __builtin_amdgcn_rcpf(P * QR);
      c[m] = cn;
      float C2 = __builtin_amdgcn_exp2f(cn * (2.0f * L2E));  // e^{2*cn}
      float hn = (C2 - 1.f) * __builtin_amdgcn_rcpf((C2 + 1.f) * (1.f + d));
      att_dot = fmaf(hn, wc[m], att_dot);
      // packed h-write: features 13p+m at slots 14p+m of row v
      if (m & 1) {
        unsigned pk;
        asm("v_cvt_pk_bf16_f32 %0, %1, %2" : "=v"(pk) : "v"(hprev), "v"(hn));
        hlw[wbase + (m >> 1)] = pk;
      } else if (m == NTILE - 1) {
        hl[v * HSTRIDE + 14 * p + 12] = f2bf(hn);
      } else {
        hprev = hn;
      }
      if (m < NTILE - 1) {   // issue next tile's MFMA after this tile's math
        f32x4 z4 = {0.f, 0.f, 0.f, 0.f};
        f32x4 t0 = __builtin_amdgcn_mfma_f32_16x16x32_bf16(x0, B0, z4, 0, 0, 0);
        accbuf[(m + 1) & 1] = __builtin_amdgcn_mfma_f32_16x16x32_bf16(x1, B1, t0, 0, 0, 0);
      }
    }
    att_dot += __shfl_xor(att_dot, 16, 64);
    att_dot += __shfl_xor(att_dot, 32, 64);
    float e2 = __builtin_amdgcn_exp2f(att_dot + bcomb);   // wc prefolded -TEMP*log2e
    float att = __builtin_amdgcn_rcpf(1.f + e2);

    // IDM: p-even leader, p-odd merger; combine via shfl_xor 16
    const float* sp = srow + t * 7;
    float vel = sp[0];
    float dvs = sp[2 + sel], dxs = sp[3 + sel];
    float r = vel * inv_dv;
    float r2 = r * r;
    float r4 = r2 * r2;
    float base = jamx + tgap * vel;
    float g = (base + vel * dvs * inv2s) * __builtin_amdgcn_rcpf(dxs);
    float fs = amax * (1.f - r4 - g * g);
    fs = fminf(fmaxf(fs, -3.5f), 3.5f);
    float fo = __shfl_xor(fs, 16, 64);
    float act = att * fs + (1.f - att) * fo;
    if (p == 0) {
      out_act[ob + t] = act;
      out_att[ob + t] = att;
    }
  }
}

extern "C" void kernel_launch(void* const* d_in, const int* in_sizes, int n_in,
                              void* d_out, int out_size, void* d_ws, size_t ws_size,
                              hipStream_t stream) {
  const float* s   = (const float*)d_in[0];
  const float* z   = (const float*)d_in[1];
  const float* dv  = (const float*)d_in[2];
  const float* tg  = (const float*)d_in[3];
  const float* jx  = (const float*)d_in[4];
  const float* ma  = (const float*)d_in[5];
  const float* mi  = (const float*)d_in[6];
  const float* h0  = (const float*)d_in[7];
  const float* c0  = (const float*)d_in[8];
  const float* Wl  = (const float*)d_in[9];
  const float* Ul  = (const float*)d_in[10];
  const float* bl  = (const float*)d_in[11];
  const float* Wa  = (const float*)d_in[12];
  const float* ba  = (const float*)d_in[13];
  const float* Wn  = (const float*)d_in[14];
  const float* bn  = (const float*)d_in[15];
  const int B = in_sizes[2];
  float* out_act = (float*)d_out;
  float* out_att = out_act + (size_t)B * NT;
  const int grid = (B + 63) / 64;
  const size_t need = (size_t)2 * NTILE * 64 * 8 * sizeof(unsigned short) + 64 * sizeof(float);
  if (d_ws && ws_size >= need) {
    unsigned short* Af = (unsigned short*)d_ws;
    float* wcb = (float*)(Af + 2 * NTILE * 64 * 8);
    idm_prep<<<1, 256, 0, stream>>>(Ul, Wl, bl, Wa, ba, Wn, bn, Af, wcb);
    idm_main<1><<<grid, 256, 0, stream>>>(s, z, dv, tg, jx, ma, mi, h0, c0, Af, wcb,
                                          Ul, Wl, bl, Wa, ba, Wn, bn, out_act, out_att, B);
  } else {
    idm_main<0><<<grid, 256, 0, stream>>>(s, z, dv, tg, jx, ma, mi, h0, c0, nullptr, nullptr,
                                          Ul, Wl, bl, Wa, ba, Wn, bn, out_act, out_att, B);
  }
}

// Round 9
// 293.730 us; speedup vs baseline: 1.0411x; 1.0411x over previous
//
#include <hip/hip_runtime.h>

#define ENC 50
#define NT 20
#define TEMPC 5.0f
#define HSTRIDE 72   // bf16 slots per batch row in LDS h-tile (64 used + pad)
#define L2E 1.4426950408889634f
#define NTILE 13
#define NREG 4       // A tiles 0..3 in registers
#define NLDS 9       // A tiles 4..12 in LDS

typedef __attribute__((ext_vector_type(8))) short bf16x8;
typedef __attribute__((ext_vector_type(4))) float f32x4;

__device__ __forceinline__ unsigned short f2bf(float x) {
  union { float f; unsigned u; } cv; cv.f = x;
  unsigned u = cv.u;
  u += 0x7FFFu + ((u >> 16) & 1u);   // RNE
  return (unsigned short)(u >> 16);
}

// k-slot layout of h~ row (64 slots): slot 14q+j (q=0..3, j=0..12) = feature 13q+j
// (features >=50 are zero-pads); j=13 pad; slot 56=z0, 57=z1, 58=const1, 59..63 pad.
// A perm: fragment m, subrow 4*pa+r -> feature 13*pa+m, gate r (i,f,g,o).
// exp2-domain prefold: gates i/f/o scaled -log2e, gate g +2*log2e.
__device__ __forceinline__ float a_elem(int m, int lane, int kt, int e,
                                        const float* U, const float* Wl,
                                        const float* bl) {
  int sub = lane & 15;
  int pa = sub >> 2, r = sub & 3;
  int feat = 13 * pa + m;
  int k = 32 * kt + 8 * (lane >> 4) + e;
  float val = 0.f;
  if (feat < ENC) {
    int col = r * ENC + feat;
    if (k < 56) {
      int pk = k / 14, j = k - 14 * pk;
      int fin = 13 * pk + j;
      if (j < 13 && fin < ENC) val = U[fin * 4 * ENC + col];
    } else if (k == 56) val = Wl[col];
    else if (k == 57)   val = Wl[4 * ENC + col];
    else if (k == 58)   val = bl[col];
  }
  return val * ((r == 2) ? (2.0f * L2E) : (-L2E));
}

__global__ void idm_prep(const float* __restrict__ U, const float* __restrict__ Wl,
                         const float* __restrict__ bl, const float* __restrict__ Wa,
                         const float* __restrict__ ba, const float* __restrict__ Wn,
                         const float* __restrict__ bn,
                         unsigned short* __restrict__ Afrag, float* __restrict__ wcomb) {
  int tid = blockIdx.x * blockDim.x + threadIdx.x;
  for (int idx = tid; idx < 2 * NTILE * 64; idx += blockDim.x * gridDim.x) {
    int frag = idx >> 6, lane = idx & 63;
    int m = frag >> 1, kt = frag & 1;
    unsigned short o[8];
#pragma unroll
    for (int e = 0; e < 8; ++e) o[e] = f2bf(a_elem(m, lane, kt, e, U, Wl, bl));
#pragma unroll
    for (int e = 0; e < 8; ++e) Afrag[idx * 8 + e] = o[e];
  }
  if (tid < 52) {
    float s = 0.f;
    if (tid < ENC) { for (int j = 0; j < ENC; ++j) s += Wa[tid * ENC + j] * Wn[j]; }
    wcomb[tid] = s * (-TEMPC * L2E);
  }
  if (tid == 52) {
    float s = bn[0];
    for (int j = 0; j < ENC; ++j) s += ba[j] * Wn[j];
    wcomb[52] = s * (-TEMPC * L2E);
  }
}

template <int PRE>
__global__ __launch_bounds__(256, 3) void idm_main(
    const float* __restrict__ s_in, const float* __restrict__ zin,
    const float* __restrict__ dvp, const float* __restrict__ tgp,
    const float* __restrict__ jxp, const float* __restrict__ map,
    const float* __restrict__ mip, const float* __restrict__ h0,
    const float* __restrict__ c0,
    const unsigned short* __restrict__ Afrag, const float* __restrict__ wcomb,
    const float* __restrict__ U, const float* __restrict__ Wl, const float* __restrict__ bl,
    const float* __restrict__ Wa, const float* __restrict__ ba,
    const float* __restrict__ Wn, const float* __restrict__ bn,
    float* __restrict__ out_act, float* __restrict__ out_att, int Btot) {
  __shared__ __align__(16) unsigned short AldT[NLDS * 2 * 64 * 8];
  __shared__ __align__(16) unsigned short hlds[4 * 16 * HSTRIDE];
  __shared__ float wcl[64];
  const int tid = threadIdx.x;
  const int wid = tid >> 6, lane = tid & 63;
  const int v = lane & 15, p = lane >> 4;
  int b = blockIdx.x * 64 + wid * 16 + v;
  if (b >= Btot) b = Btot - 1;   // benign duplicate work

  bf16x8 Ar[NREG][2];
  float wc[NTILE], bcomb;
  if (PRE) {
#pragma unroll
    for (int m = 0; m < NREG; ++m) {
      Ar[m][0] = ((const bf16x8*)Afrag)[(2 * m) * 64 + lane];
      Ar[m][1] = ((const bf16x8*)Afrag)[(2 * m + 1) * 64 + lane];
    }
    {
      f32x4* dst = (f32x4*)AldT;
      const f32x4* src = (const f32x4*)Afrag + NREG * 2 * 64;
      for (int i = tid; i < NLDS * 2 * 64; i += 256) dst[i] = src[i];
    }
#pragma unroll
    for (int m = 0; m < NTILE; ++m) wc[m] = wcomb[13 * p + m];
    bcomb = wcomb[52];
  } else {
    if (tid < 53) {
      float s;
      if (tid < ENC) {
        s = 0.f;
        for (int j = 0; j < ENC; ++j) s += Wa[tid * ENC + j] * Wn[j];
      } else if (tid < 52) {
        s = 0.f;
      } else {
        s = bn[0];
        for (int j = 0; j < ENC; ++j) s += ba[j] * Wn[j];
      }
      wcl[tid] = s * (-TEMPC * L2E);
    } else if (tid < 64) {
      wcl[tid] = 0.f;
    }
#pragma unroll
    for (int m = 0; m < NREG; ++m) {
#pragma unroll
      for (int kt = 0; kt < 2; ++kt) {
        bf16x8 a;
#pragma unroll
        for (int e = 0; e < 8; ++e) a[e] = (short)f2bf(a_elem(m, lane, kt, e, U, Wl, bl));
        Ar[m][kt] = a;
      }
    }
    for (int q = wid; q < NLDS * 2; q += 4) {   // waves split the LDS tiles
      int m = NREG + (q >> 1), kt = q & 1;
      unsigned short o[8];
#pragma unroll
      for (int e = 0; e < 8; ++e) o[e] = f2bf(a_elem(m, lane, kt, e, U, Wl, bl));
      bf16x8 a;
#pragma unroll
      for (int e = 0; e < 8; ++e) a[e] = (short)o[e];
      ((bf16x8*)AldT)[q * 64 + lane] = a;
    }
    __syncthreads();
#pragma unroll
    for (int m = 0; m < NTILE; ++m) wc[m] = wcl[13 * p + m];
    bcomb = wcl[52];
  }
  __syncthreads();   // A-LDS staged (and wcl in non-PRE)

  // per-row params (cached)
  const float amax = map[b], amin = mip[b];
  const float tgap = tgp[b], jamx = jxp[b];
  const float inv_dv = __builtin_amdgcn_rcpf(dvp[b]);
  const float inv2s = 0.5f * __builtin_amdgcn_rsqf(amax * amin);

  // c state: feature 13p+m of batch b
  float c[NTILE];
#pragma unroll
  for (int m = 0; m < NTILE; ++m) {
    int f = 13 * p + m;
    c[m] = (f < ENC) ? c0[(size_t)b * ENC + f] : 0.f;
  }

  // init h~ LDS region for this wave
  unsigned short* hl = &hlds[wid * 16 * HSTRIDE];
  for (int i = lane; i < 16 * HSTRIDE / 2; i += 64) ((unsigned*)hl)[i] = 0u;
#pragma unroll
  for (int m = 0; m < NTILE; ++m) {
    int f = 13 * p + m;
    float h00 = (f < ENC) ? h0[(size_t)b * ENC + f] : 0.f;
    hl[v * HSTRIDE + 14 * p + m] = f2bf(h00);
  }
  if (p == 0) {
    hl[v * HSTRIDE + 56] = f2bf(zin[(size_t)b * 2 + 0]);
    hl[v * HSTRIDE + 57] = f2bf(zin[(size_t)b * 2 + 1]);
    hl[v * HSTRIDE + 58] = (unsigned short)0x3F80; // bf16(1.0)
  }

  const float* srow = s_in + (size_t)b * (NT * 7);
  const size_t ob = (size_t)b * NT;
  const bf16x8* hv = (const bf16x8*)hl;
  const int sel = 3 * (p & 1);   // p even: leader; p odd: merger
  unsigned* hlw = (unsigned*)hl;
  const int wbase = v * 36 + 7 * p;        // dword index of this lane's h slots
  unsigned aoff = 0;                       // opaque: defeats LICM of A-LDS reads

#pragma unroll 1
  for (int t = 0; t < NT; ++t) {
    asm volatile("" : "+v"(aoff));
    const bf16x8* ATv = (const bf16x8*)AldT + aoff;
    // B-fragments: slots [8p,8p+8) and [32+8p, 32+8p+8) of row v
    bf16x8 B0 = hv[v * 9 + p];
    bf16x8 B1 = hv[v * 9 + 4 + p];
    f32x4 accbuf[2];
    {
      f32x4 z4 = {0.f, 0.f, 0.f, 0.f};
      f32x4 t0 = __builtin_amdgcn_mfma_f32_16x16x32_bf16(Ar[0][0], B0, z4, 0, 0, 0);
      accbuf[0] = __builtin_amdgcn_mfma_f32_16x16x32_bf16(Ar[0][1], B1, t0, 0, 0, 0);
    }
    float att_dot = 0.f;
    float hprev = 0.f;
#pragma unroll
    for (int m = 0; m < NTILE; ++m) {
      f32x4 acc = accbuf[m & 1];
      // lane-local LSTM cell in exp2 domain: acc = {-i*L2E, -f*L2E, 2g*L2E, -o*L2E}
      float a  = __builtin_amdgcn_exp2f(acc[0]);   // e^{-i}
      float bb = __builtin_amdgcn_exp2f(acc[1]);   // e^{-f}
      float G  = __builtin_amdgcn_exp2f(acc[2]);   // e^{2g}
      float d  = __builtin_amdgcn_exp2f(acc[3]);   // e^{-o}
      float R = 1.f + a, P = 1.f + bb, Q = G + 1.f;
      float QR = Q * R;
      float num = fmaf(G - 1.f, P, c[m] * QR);
      float cn = num * __builtin_amdgcn_rcpf(P * QR);
      c[m] = cn;
      float C2 = __builtin_amdgcn_exp2f(cn * (2.0f * L2E));  // e^{2*cn}
      float hn = (C2 - 1.f) * __builtin_amdgcn_rcpf((C2 + 1.f) * (1.f + d));
      att_dot = fmaf(hn, wc[m], att_dot);
      // packed h-write: features 13p+m at slots 14p+m of row v
      if (m & 1) {
        unsigned pk;
        asm("v_cvt_pk_bf16_f32 %0, %1, %2" : "=v"(pk) : "v"(hprev), "v"(hn));
        hlw[wbase + (m >> 1)] = pk;
      } else if (m == NTILE - 1) {
        hl[v * HSTRIDE + 14 * p + 12] = f2bf(hn);
      } else {
        hprev = hn;
      }
      if (m < NTILE - 1) {   // load + issue next tile's MFMA (no early prefetch:
        bf16x8 x0, x1;       //  ds_read sits at its MFMA -> minimal live range)
        if (m + 1 < NREG) {
          x0 = Ar[m + 1][0]; x1 = Ar[m + 1][1];
        } else {
          int q = (m + 1 - NREG) * 2;
          x0 = ATv[q * 64 + lane];
          x1 = ATv[(q + 1) * 64 + lane];
        }
        f32x4 z4 = {0.f, 0.f, 0.f, 0.f};
        f32x4 t0 = __builtin_amdgcn_mfma_f32_16x16x32_bf16(x0, B0, z4, 0, 0, 0);
        accbuf[(m + 1) & 1] = __builtin_amdgcn_mfma_f32_16x16x32_bf16(x1, B1, t0, 0, 0, 0);
      }
    }
    att_dot += __shfl_xor(att_dot, 16, 64);
    att_dot += __shfl_xor(att_dot, 32, 64);
    float e2 = __builtin_amdgcn_exp2f(att_dot + bcomb);   // wc prefolded -TEMP*log2e
    float att = __builtin_amdgcn_rcpf(1.f + e2);

    // IDM: p-even leader, p-odd merger; combine via shfl_xor 16
    const float* sp = srow + t * 7;
    float vel = sp[0];
    float dvs = sp[2 + sel], dxs = sp[3 + sel];
    float r = vel * inv_dv;
    float r2 = r * r;
    float r4 = r2 * r2;
    float base = jamx + tgap * vel;
    float g = (base + vel * dvs * inv2s) * __builtin_amdgcn_rcpf(dxs);
    float fs = amax * (1.f - r4 - g * g);
    fs = fminf(fmaxf(fs, -3.5f), 3.5f);
    float fo = __shfl_xor(fs, 16, 64);
    float act = att * fs + (1.f - att) * fo;
    if (p == 0) {
      out_act[ob + t] = act;
      out_att[ob + t] = att;
    }
  }
}

extern "C" void kernel_launch(void* const* d_in, const int* in_sizes, int n_in,
                              void* d_out, int out_size, void* d_ws, size_t ws_size,
                              hipStream_t stream) {
  const float* s   = (const float*)d_in[0];
  const float* z   = (const float*)d_in[1];
  const float* dv  = (const float*)d_in[2];
  const float* tg  = (const float*)d_in[3];
  const float* jx  = (const float*)d_in[4];
  const float* ma  = (const float*)d_in[5];
  const float* mi  = (const float*)d_in[6];
  const float* h0  = (const float*)d_in[7];
  const float* c0  = (const float*)d_in[8];
  const float* Wl  = (const float*)d_in[9];
  const float* Ul  = (const float*)d_in[10];
  const float* bl  = (const float*)d_in[11];
  const float* Wa  = (const float*)d_in[12];
  const float* ba  = (const float*)d_in[13];
  const float* Wn  = (const float*)d_in[14];
  const float* bn  = (const float*)d_in[15];
  const int B = in_sizes[2];
  float* out_act = (float*)d_out;
  float* out_att = out_act + (size_t)B * NT;
  const int grid = (B + 63) / 64;
  const size_t need = (size_t)2 * NTILE * 64 * 8 * sizeof(unsigned short) + 64 * sizeof(float);
  if (d_ws && ws_size >= need) {
    unsigned short* Af = (unsigned short*)d_ws;
    float* wcb = (float*)(Af + 2 * NTILE * 64 * 8);
    idm_prep<<<1, 256, 0, stream>>>(Ul, Wl, bl, Wa, ba, Wn, bn, Af, wcb);
    idm_main<1><<<grid, 256, 0, stream>>>(s, z, dv, tg, jx, ma, mi, h0, c0, Af, wcb,
                                          Ul, Wl, bl, Wa, ba, Wn, bn, out_act, out_att, B);
  } else {
    idm_main<0><<<grid, 256, 0, stream>>>(s, z, dv, tg, jx, ma, mi, h0, c0, nullptr, nullptr,
                                          Ul, Wl, bl, Wa, ba, Wn, bn, out_act, out_att, B);
  }
}